// Round 1
// baseline (955.350 us; speedup 1.0000x reference)
//
#include <hip/hip_runtime.h>

// Problem constants (fixed by the reference harness).
constexpr int  BSc = 16;
constexpr int  Gc  = 8;
constexpr int  Sc  = 4096;   // cache sequence length (power of 2)
constexpr int  Hc  = 128;    // head size
constexpr int  Tc  = 2048;   // new positions written
constexpr int  H4  = Hc / 4; // float4 per row = 32 (power of 2)

constexpr long N_EACH  = (long)BSc * Gc * Sc * Hc; // 67,108,864 elems per output tensor
constexpr long N4_EACH = N_EACH / 4;               // 16,777,216 float4 per output tensor
constexpr long NK4     = (long)BSc * Gc * Tc * Hc / 4; // float4 count in k (and v)

// ---- idx_map build: idx_map[s] = t if input_pos[t] == s else -1 -------------
__global__ void init_idx_kernel(int* __restrict__ idx_map) {
    int i = blockIdx.x * blockDim.x + threadIdx.x;
    if (i < Sc) idx_map[i] = -1;
}

__global__ void scatter_idx_kernel(const int* __restrict__ pos,
                                   int* __restrict__ idx_map) {
    int t = blockIdx.x * blockDim.x + threadIdx.x;
    if (t < Tc) {
        int p = pos[t];
        if (p >= 0 && p < Sc) idx_map[p] = t; // duplicates: some writer wins (matches .at[].set)
    }
}

// ---- single gather pass: each output float4 sourced from k/v or cache -------
__global__ __launch_bounds__(256) void kv_gather_kernel(
    const float4* __restrict__ k,  const float4* __restrict__ v,
    const float4* __restrict__ ck, const float4* __restrict__ cv,
    const int*    __restrict__ idx_map,
    float4* __restrict__ outk, float4* __restrict__ outv)
{
    const long stride = (long)gridDim.x * blockDim.x;
    for (long i = (long)blockIdx.x * blockDim.x + threadIdx.x; i < N4_EACH; i += stride) {
        const long row = i >> 5;                 // /H4: global row index (b,g,s)
        const int  col = (int)(i & (H4 - 1));    // float4 within the 128-elem row
        const int  s   = (int)(row & (Sc - 1));  // seq position
        const long bg  = row >> 12;              // /Sc: (b*G + g)
        const int  t   = idx_map[s];             // L1-resident (16 KB)

        const long  src = (t >= 0) ? ((bg * Tc + t) * H4 + col) : i;
        const float4* pk = (t >= 0) ? k : ck;
        const float4* pv = (t >= 0) ? v : cv;

        outk[i] = pk[src];
        outv[i] = pv[src];
    }
}

// ---- fallback (no workspace): copy caches, then scatter k/v -----------------
__global__ __launch_bounds__(256) void copy_cache_kernel(
    const float4* __restrict__ ck, const float4* __restrict__ cv,
    float4* __restrict__ outk, float4* __restrict__ outv)
{
    const long stride = (long)gridDim.x * blockDim.x;
    for (long i = (long)blockIdx.x * blockDim.x + threadIdx.x; i < N4_EACH; i += stride) {
        outk[i] = ck[i];
        outv[i] = cv[i];
    }
}

__global__ __launch_bounds__(256) void scatter_kv_kernel(
    const int* __restrict__ pos,
    const float4* __restrict__ k, const float4* __restrict__ v,
    float4* __restrict__ outk, float4* __restrict__ outv)
{
    const long stride = (long)gridDim.x * blockDim.x;
    for (long i = (long)blockIdx.x * blockDim.x + threadIdx.x; i < NK4; i += stride) {
        const long row = i >> 5;               // (b*G+g)*T + t
        const int  col = (int)(i & (H4 - 1));
        const int  t   = (int)(row % Tc);
        const long bg  = row / Tc;
        const int  s   = pos[t];
        const long dst = (bg * Sc + s) * H4 + col;
        outk[dst] = k[i];
        outv[dst] = v[i];
    }
}

extern "C" void kernel_launch(void* const* d_in, const int* in_sizes, int n_in,
                              void* d_out, int out_size, void* d_ws, size_t ws_size,
                              hipStream_t stream) {
    const int*    pos = (const int*)d_in[0];
    const float4* k   = (const float4*)d_in[1];
    const float4* v   = (const float4*)d_in[2];
    const float4* ck  = (const float4*)d_in[3];
    const float4* cv  = (const float4*)d_in[4];

    float4* outk = (float4*)d_out;
    float4* outv = outk + N4_EACH;

    if (ws_size >= Sc * sizeof(int)) {
        int* idx_map = (int*)d_ws;
        init_idx_kernel<<<(Sc + 255) / 256, 256, 0, stream>>>(idx_map);
        scatter_idx_kernel<<<(Tc + 255) / 256, 256, 0, stream>>>(pos, idx_map);
        kv_gather_kernel<<<2048, 256, 0, stream>>>(k, v, ck, cv, idx_map, outk, outv);
    } else {
        copy_cache_kernel<<<2048, 256, 0, stream>>>(ck, cv, outk, outv);
        scatter_kv_kernel<<<2048, 256, 0, stream>>>(pos, k, v, outk, outv);
    }
}